// Round 7
// baseline (155.392 us; speedup 1.0000x reference)
//
#include <hip/hip_runtime.h>

#define MA 64
#define F 128
#define NF 16
#define HID 512
#define LDUB 144    // ub row stride BYTES (128 fp8 + 16 pad)
#define LDWB 144    // wL row stride bytes (64 bf16 + 8 pad elems)
#define LDT1B 1040  // t1 row stride bytes (512 bf16 + 8 pad elems)
// double-buffer base offsets (bytes)
#define UB0 0
#define UB1 9216
#define WL0 18432
#define WL1 27648

typedef float  float4v  __attribute__((ext_vector_type(4)));
typedef float  float16v __attribute__((ext_vector_type(16)));
typedef short  short8   __attribute__((ext_vector_type(8)));
typedef int    int8v    __attribute__((ext_vector_type(8)));

// pack two fp32 -> (bf16(y)<<16)|bf16(x), round-half-up via +0x8000 then v_perm
static __device__ __forceinline__ unsigned int pack2bf(float x, float y) {
    unsigned int a = __float_as_uint(x) + 0x8000u;
    unsigned int b = __float_as_uint(y) + 0x8000u;
    return __builtin_amdgcn_perm(b, a, 0x07060302u);
}
static __device__ __forceinline__ unsigned short f2bf1(float x) {
    return (unsigned short)((__float_as_uint(x) + 0x8000u) >> 16);
}
// pack 4 fp32 -> 4 fp8 e4m3 (RNE, saturating) in one dword
static __device__ __forceinline__ unsigned int pk4fp8(float a, float b, float c, float d) {
    int p = __builtin_amdgcn_cvt_pk_fp8_f32(a, b, 0, false);
    p = __builtin_amdgcn_cvt_pk_fp8_f32(c, d, p, true);
    return (unsigned int)p;
}

// lgkm-only barrier: LDS producer/consumer sync WITHOUT draining vmcnt, so
// global prefetches (afr / aw2) stay in flight across the rendezvous.
#define LGKM_BAR() do {                                        \
    asm volatile("s_waitcnt lgkmcnt(0)" ::: "memory");         \
    __builtin_amdgcn_s_barrier();                              \
    asm volatile("" ::: "memory");                             \
} while (0)

// ---- Pack W1 as fp8 MX A-frags for 32x32x64 (lane l holds A[m=l&31][k=(l>>5)*32+j],
// j=0..31 bytes) of W1^T, per (kt2 = 64-K-half over 2176, jt = j-tile-32); W2 as bf16
// A-frags (16x16x32) of W2^T. Direct gather.
__global__ void pack_frags(const float* __restrict__ W1, const float* __restrict__ W2,
                           unsigned char* __restrict__ w1p, unsigned short* __restrict__ w2p) {
    int gid  = blockIdx.x * 4 + (threadIdx.x >> 6);
    int lane = threadIdx.x & 63;
    if (gid < 544) {                           // W1: kt2 (34 over K=2176, 64 each) x jt (16 over 512)
        int kt2 = gid >> 4, jt = gid & 15;
        int m  = lane & 31;                    // output row (W1 col)
        int ks = lane >> 5;                    // k sub-half (32)
        const float* base = W1 + (size_t)(kt2 * 64 + ks * 32) * HID + jt * 32 + m;
        unsigned int o[8];
        #pragma unroll
        for (int p = 0; p < 8; p++)
            o[p] = pk4fp8(base[(p * 4 + 0) * HID], base[(p * 4 + 1) * HID],
                          base[(p * 4 + 2) * HID], base[(p * 4 + 3) * HID]);
        unsigned char* dst = w1p + ((size_t)gid * 64 + lane) * 32;
        *(uint4*)dst        = (uint4){o[0], o[1], o[2], o[3]};
        *(uint4*)(dst + 16) = (uint4){o[4], o[5], o[6], o[7]};
    } else if (gid < 544 + 128) {              // W2: kt (16 over J=512) x mt (8 over 128)
        int g2 = gid - 544;
        int arow = lane & 15;
        int kq   = lane >> 4;
        int kt = g2 >> 3, mt = g2 & 7;
        const float* base = W2 + (size_t)(kt * 32 + kq * 8) * F + mt * 16 + arow;
        short8 o;
        #pragma unroll
        for (int j = 0; j < 8; j++) o[j] = (short)f2bf1(base[j * F]);
        *(short8*)(w2p + ((size_t)g2 * 64 + lane) * 8) = o;
    }
}

// ---- Main fused kernel: ONE molecule per block, 1024 threads = 16 waves ----
// 4 waves/SIMD. LDS-TRAFFIC-MINIMIZED partitions (was the binder: ~208KB
// LDS/interval/CU ~= interval duration):
//  GEMM1: 32x32x64 MX MFMAs, wave owns 2 j-tiles-32 (jt0=(wave&7)*2) x 1
//   a-tile-32 (atb=wave>>3): ub B-reads halve to 64KB/interval; W1 A-frags
//   (8KB/wave, L2) are prefetched a FULL interval ahead and ride vmcnt
//   across the barrier (r4's mid-GEMM blocking load avoided).
//  u-GEMM: wave owns 1 a-tile-16 (uat=wave&3) x 2 c-tiles (uct0=(wave>>2)*2):
//   each bw read feeds both c-slices -> wL reads halve to 32KB/interval.
// acc[2] x 16 = 32 AGPR unchanged.
__launch_bounds__(1024, 4)
__global__ void node_conv_mfma(const int* __restrict__ z, const float* __restrict__ rr,
        const float* __restrict__ h, const float* __restrict__ dist,
        const float* __restrict__ wid, const float* __restrict__ b1,
        const float* __restrict__ b2,
        const unsigned char* __restrict__ w1p, const unsigned short* __restrict__ w2p,
        float* __restrict__ out) {
    const int n = blockIdx.x;                  // molecule index
    const int tid = threadIdx.x;
    const int lane = tid & 63;
    const int wave = tid >> 6;                 // 0..15
    const int arow = lane & 15;
    const int quad = lane >> 4;
    const int kgrp = quad * 8;
    const int arow31 = lane & 31;              // 32x32 fragment row/col
    const int khalf  = lane >> 5;              // 32x32 fragment k-half
    const int jt0 = (wave & 7) * 2;            // GEMM1: first of 2 j-tiles-32
    const int atb = wave >> 3;                 // GEMM1: a-tile-32 (0/1)
    const int uat  = wave & 3;                 // u-GEMM: a-tile-16
    const int uct0 = (wave >> 2) * 2;          // u-GEMM: first of 2 c-tiles-16
    const int whi = wave >> 1;                 // GEMM2: c-tile
    const int wlo = wave & 1;                  // GEMM2: a-pair selector

    __shared__ __attribute__((aligned(16))) unsigned char lds[66560];
    __shared__ float r_lds[MA][5];             // xyz + mask, stride-5

    const int N = gridDim.x;
    const float* hg = h + (size_t)n * MA * F;

    // ---- z / r passthrough + r/mask staging ----
    if (tid < MA) {
        int zi = z[n * MA + tid];
        out[(size_t)n * MA + tid] = (float)zi;
        r_lds[tid][0] = rr[(n * MA + tid) * 3 + 0];
        r_lds[tid][1] = rr[(n * MA + tid) * 3 + 1];
        r_lds[tid][2] = rr[(n * MA + tid) * 3 + 2];
        r_lds[tid][3] = (zi > -1) ? 1.0f : 0.0f;
    }
    if (tid < MA * 3)
        out[(size_t)N * MA + (size_t)n * MA * 3 + tid] = rr[(size_t)n * MA * 3 + tid];

    // ---- stage h -> ub0 (row-major fp8) ----
    for (int i = tid; i < MA * F / 4; i += 1024) {
        float4 v = ((const float4*)hg)[i];
        int a = i >> 5, c4 = (i & 31) * 4;
        *(unsigned int*)&lds[UB0 + a * LDUB + c4] = pk4fp8(v.x, v.y, v.z, v.w);
    }
    // ---- hT A-fragments in registers (bf16) for u-GEMM: 2 c-slices.
    // lane holds h[b][c], c = (uct0+cc)*16+arow, b = ks2*32+kgrp+j ----
    short8 ah2[2][2];
    #pragma unroll
    for (int cc = 0; cc < 2; cc++) {
        int c = (uct0 + cc) * 16 + arow;
        #pragma unroll
        for (int ks2 = 0; ks2 < 2; ks2++)
            #pragma unroll
            for (int j = 0; j < 8; j++)
                ah2[cc][ks2][j] = (short)f2bf1(hg[(size_t)(ks2 * 32 + kgrp + j) * F + c]);
    }
    __syncthreads();                           // r_lds + ub0 staged h visible (full drain, once)

    // ---- per-thread pairwise distances (4 pairs/thread), mask folded in ----
    const int wa = tid >> 4;                   // 0..63
    const int wb0 = (tid & 15) * 4;            // 0,4,..,60
    float dpre[4];
    {
        float ax = r_lds[wa][0], ay = r_lds[wa][1], az = r_lds[wa][2];
        float am = r_lds[wa][3];
        #pragma unroll
        for (int j = 0; j < 4; j++) {
            float dx = ax - r_lds[wb0 + j][0];
            float dy = ay - r_lds[wb0 + j][1];
            float dz = az - r_lds[wb0 + j][2];
            float d = sqrtf(dx * dx + dy * dy + dz * dz + 1e-12f);
            float mm = am * r_lds[wb0 + j][3];
            dpre[j] = d + (1.0f - mm) * 1e4f;
        }
    }

    // ---- prime: w filter 0 -> wL0 (bf16), A-frags for seg 0 (4 x 32B) ----
    {
        float mu = dist[0];
        float isg = 1.0f / wid[0];
        float e[4];
        #pragma unroll
        for (int j = 0; j < 4; j++) {
            float t = dpre[j] - mu;
            e[j] = 5.0f * __expf(-t * t * isg);
        }
        uint2 wp = { pack2bf(e[0], e[1]), pack2bf(e[2], e[3]) };
        *(uint2*)&lds[WL0 + wa * LDWB + wb0 * 2] = wp;
    }
    // A-frags: af[jj][kh], frag id = (f*2+kh)*16 + (jt0+jj)
    int8v af00, af01, af10, af11;
    {
        const unsigned char* p0 = w1p + ((size_t)(0 * 16 + jt0) * 64 + lane) * 32;   // kh=0
        const unsigned char* p1 = w1p + ((size_t)(1 * 16 + jt0) * 64 + lane) * 32;   // kh=1
        af00 = *(const int8v*)p0;
        af10 = *(const int8v*)(p0 + 2048);
        af01 = *(const int8v*)p1;
        af11 = *(const int8v*)(p1 + 2048);
    }
    LGKM_BAR();                                // w0 + ub0 visible; af loads ride through

    const float4v zf = {0.f, 0.f, 0.f, 0.f};
    float16v acc[2];                           // [jj] 32x32 tiles = 32 AGPRs
    #pragma unroll
    for (int i = 0; i < 2; i++)
        #pragma unroll
        for (int r = 0; r < 16; r++) acc[i][r] = 0.f;

    // ---- main loop: 17 K-segments of 128, ONE lgkm barrier per iteration ----
    for (int f = 0; f <= NF; f++) {
        const int sel = f & 1;
        const int ubR = sel ? UB1 : UB0;
        const int ubW = sel ? UB0 : UB1;
        const int wlR = sel ? WL1 : WL0;
        const int wlW = sel ? WL0 : WL1;

        // GEMM1 seg f: 4 x 32x32x64 MX MFMA. B-frag: lane holds
        // ub[atb*32 + (l&31)][kh*64 + (l>>5)*32 + j], j=0..31 (E8M0 127 = 1.0)
        {
            const int rowb = ubR + (atb * 32 + arow31) * LDUB + khalf * 32;
            int8v bfrA = *(const int8v*)&lds[rowb];        // kh = 0
            int8v bfrB = *(const int8v*)&lds[rowb + 64];   // kh = 1
            acc[0] = __builtin_amdgcn_mfma_scale_f32_32x32x64_f8f6f4(
                af00, bfrA, acc[0], 0, 0, 0, 127, 0, 127);
            acc[1] = __builtin_amdgcn_mfma_scale_f32_32x32x64_f8f6f4(
                af10, bfrA, acc[1], 0, 0, 0, 127, 0, 127);
            acc[0] = __builtin_amdgcn_mfma_scale_f32_32x32x64_f8f6f4(
                af01, bfrB, acc[0], 0, 0, 0, 127, 0, 127);
            acc[1] = __builtin_amdgcn_mfma_scale_f32_32x32x64_f8f6f4(
                af11, bfrB, acc[1], 0, 0, 0, 127, 0, 127);
        }

        if (f < NF) {
            // prefetch ALL of next segment's A-frags now (WAR on af regs; the
            // loads have u-GEMM + exp + barrier + next bfr reads to complete,
            // riding vmcnt across the lgkm-only barrier)
            const unsigned char* p0 = w1p + ((size_t)(((f + 1) * 2 + 0) * 16 + jt0) * 64 + lane) * 32;
            const unsigned char* p1 = w1p + ((size_t)(((f + 1) * 2 + 1) * 16 + jt0) * 64 + lane) * 32;
            af00 = *(const int8v*)p0;
            af10 = *(const int8v*)(p0 + 2048);
            af01 = *(const int8v*)p1;
            af11 = *(const int8v*)(p1 + 2048);

            // u-GEMM: u_f^T = hT @ w_f (bf16, w symmetric); wave: a-tile uat,
            // c-tiles uct0+{0,1}; each bw read feeds BOTH c-slices.
            float4v ud0 = zf, ud1 = zf;
            #pragma unroll
            for (int ks2 = 0; ks2 < 2; ks2++) {
                short8 bw = *(const short8*)&lds[wlR + (uat * 16 + arow) * LDWB + (ks2 * 32 + kgrp) * 2];
                ud0 = __builtin_amdgcn_mfma_f32_16x16x32_bf16(ah2[0][ks2], bw, ud0, 0, 0, 0);
                ud1 = __builtin_amdgcn_mfma_f32_16x16x32_bf16(ah2[1][ks2], bw, ud1, 0, 0, 0);
            }
            unsigned int u0 = pk4fp8(ud0[0], ud0[1], ud0[2], ud0[3]);
            unsigned int u1 = pk4fp8(ud1[0], ud1[1], ud1[2], ud1[3]);
            *(unsigned int*)&lds[ubW + (uat * 16 + arow) * LDUB + (uct0 + 0) * 16 + quad * 4] = u0;
            *(unsigned int*)&lds[ubW + (uat * 16 + arow) * LDUB + (uct0 + 1) * 16 + quad * 4] = u1;

            if (f <= NF - 2) {                 // exp w_{f+1} -> write buffer
                float mu = dist[f + 1];
                float isg = 1.0f / wid[f + 1];
                float e[4];
                #pragma unroll
                for (int j = 0; j < 4; j++) {
                    float t = dpre[j] - mu;
                    e[j] = 5.0f * __expf(-t * t * isg);
                }
                uint2 wp = { pack2bf(e[0], e[1]), pack2bf(e[2], e[3]) };
                *(uint2*)&lds[wlW + wa * LDWB + wb0 * 2] = wp;
            }
        }
        LGKM_BAR();                            // u_f + w_{f+1} visible / final: ub reads drained
    }

    // ---- GEMM2 (bf16): out = h + 0.1*mask*(silu(t1) @ W2 + b2) ----
    // t1 write from 32x32 acc: D[m][n]: m = (r&3)+8*(r>>2)+4*khalf (j-in-tile),
    // n = arow31 (a-in-tile). t1[a][j] = silu(acc + b1[j]).
    #pragma unroll
    for (int jj = 0; jj < 2; jj++) {
        const int jt = jt0 + jj;
        const int a  = atb * 32 + arow31;
        #pragma unroll
        for (int g = 0; g < 4; g++) {
            const int jb = jt * 32 + 4 * khalf + 8 * g;   // j of element e=0
            float4 b1q = *(const float4*)&b1[jb];
            float xs[4];
            #pragma unroll
            for (int e = 0; e < 4; e++) {
                float x = acc[jj][g * 4 + e] + ((const float*)&b1q)[e];
                xs[e] = x / (1.0f + __expf(-x));
            }
            uint2 pv = { pack2bf(xs[0], xs[1]), pack2bf(xs[2], xs[3]) };
            *(uint2*)&lds[a * LDT1B + jb * 2] = pv;
        }
    }
    LGKM_BAR();                                // full t1 visible; aw2 stream rides through

    float4v g2[2] = { zf, zf };                // this wave: c-tile whi, a-pair wlo

    short8 awA = *(const short8*)(w2p + ((size_t)(whi) * 64 + lane) * 8);   // ks=0
    #pragma unroll
    for (int ks2 = 0; ks2 < 8; ks2++) {
        const int k1 = 2 * ks2 + 1;
        short8 awB = *(const short8*)(w2p + ((size_t)(k1 * 8 + whi) * 64 + lane) * 8);
        #pragma unroll
        for (int j = 0; j < 2; j++) {
            short8 bt = *(const short8*)&lds[((wlo * 2 + j) * 16 + arow) * LDT1B + ((2 * ks2) * 32 + kgrp) * 2];
            g2[j] = __builtin_amdgcn_mfma_f32_16x16x32_bf16(awA, bt, g2[j], 0, 0, 0);
        }
        const int k2 = (ks2 < 7) ? 2 * ks2 + 2 : 0;   // harmless re-read on last iter
        awA = *(const short8*)(w2p + ((size_t)(k2 * 8 + whi) * 64 + lane) * 8);
        #pragma unroll
        for (int j = 0; j < 2; j++) {
            short8 bt = *(const short8*)&lds[((wlo * 2 + j) * 16 + arow) * LDT1B + ((2 * ks2 + 1) * 32 + kgrp) * 2];
            g2[j] = __builtin_amdgcn_mfma_f32_16x16x32_bf16(awB, bt, g2[j], 0, 0, 0);
        }
    }

    // D[m=c][n=a]: a = (wlo*2+j)*16+arow, c = whi*16 + quad*4 + r
    float* outh = out + (size_t)N * MA * 4 + (size_t)n * MA * F;
    const int c0 = whi * 16 + quad * 4;
    float4 b2v = *(const float4*)&b2[c0];
    #pragma unroll
    for (int j = 0; j < 2; j++) {
        int a = (wlo * 2 + j) * 16 + arow;
        float m = r_lds[a][3] * 0.1f;
        float4 hv = *(const float4*)&hg[a * F + c0];
        float4 res;
        res.x = hv.x + (g2[j][0] + b2v.x) * m;
        res.y = hv.y + (g2[j][1] + b2v.y) * m;
        res.z = hv.z + (g2[j][2] + b2v.z) * m;
        res.w = hv.w + (g2[j][3] + b2v.w) * m;
        *(float4*)&outh[(size_t)a * F + c0] = res;
    }
}

extern "C" void kernel_launch(void* const* d_in, const int* in_sizes, int n_in,
                              void* d_out, int out_size, void* d_ws, size_t ws_size,
                              hipStream_t stream) {
    const int*   z    = (const int*)d_in[0];
    const float* rr   = (const float*)d_in[1];
    const float* h    = (const float*)d_in[2];
    const float* dist = (const float*)d_in[3];
    const float* wid  = (const float*)d_in[4];
    const float* W1   = (const float*)d_in[5];
    const float* b1   = (const float*)d_in[6];
    const float* W2   = (const float*)d_in[7];
    const float* b2   = (const float*)d_in[8];
    float* out = (float*)d_out;

    int Nmol = in_sizes[0] / MA;                           // 512 molecules

    unsigned char*  w1p = (unsigned char*)d_ws;            // 544*64*32 = 1,114,112 B
    unsigned short* w2p = (unsigned short*)(w1p + (size_t)544 * 64 * 32);  // 128 KB bf16

    pack_frags<<<168, 256, 0, stream>>>(W1, W2, w1p, w2p);
    node_conv_mfma<<<Nmol, 1024, 0, stream>>>(z, rr, h, dist, wid, b1, b2, w1p, w2p, out);
}